// Round 2
// baseline (3922.301 us; speedup 1.0000x reference)
//
#include <hip/hip_runtime.h>
#include <hip/hip_bf16.h>

// LSTM_Sequence_Prediction — MI355X
// S=256 seq, B=64 batch, F=256 feat, H=768 hidden, L=3 layers, T=32 target.
// All harness buffers are FP32 (reference dtype). We convert x + encoder
// weights to bf16 in d_ws once, run the encoder recurrence with 16x16x32 bf16
// MFMA, and keep the (tiny) decoder/head in pure fp32.
//
// Proved simplifications:
//  - encoder layers 1..2: zero state, seq_len=1  => Whh term vanishes, c=0.
//  - decoder: zero initial hidden, no inputs     => layers independent,
//    batch-independent; only last layer feeds the head => evolve ONE 768-vec.
//  - f-gate irrelevant whenever c_prev == 0.

constexpr int NB = 64;    // batch
constexpr int NH = 768;   // hidden
constexpr int NF = 256;   // features
constexpr int NS = 256;   // seq len
constexpr int NT = 32;    // target len

typedef short bf16x8 __attribute__((ext_vector_type(8)));
typedef float f32x4 __attribute__((ext_vector_type(4)));

__device__ __forceinline__ float sigm(float x) { return 1.f / (1.f + expf(-x)); }

// fp32 -> bf16 conversion, 4 elements/thread (n % 4 == 0 for all our arrays)
__global__ __launch_bounds__(256) void cvt_f32_bf16(
    const float* __restrict__ s, __hip_bfloat16* __restrict__ d, int n)
{
    const int i = (blockIdx.x * 256 + threadIdx.x) * 4;
    if (i >= n) return;
    const float4 v = *(const float4*)(s + i);
    d[i]     = __float2bfloat16(v.x);
    d[i + 1] = __float2bfloat16(v.y);
    d[i + 2] = __float2bfloat16(v.z);
    d[i + 3] = __float2bfloat16(v.w);
}

// One LSTM step: gates = xin@Wx^T + hin@Wh^T + bih + bhh; cell; h out (+c).
// Block = 256 thr = 4 waves; wave g computes gate g for a 16-unit tile over 32
// batch rows (grid = 48 unit-tiles x 2 batch halves = 96 blocks).
// MFMA 16x16x32 bf16, fp32 accum; gates exchanged through LDS for the fused
// cell epilogue (all 4 gates of a unit live in the same block by construction).
template<int KX, int KH>
__global__ __launch_bounds__(256) void lstm_step(
    const __hip_bfloat16* __restrict__ xin,   // NB x KX  (bf16)
    const __hip_bfloat16* __restrict__ hin,   // NB x KH  (bf16, null if KH==0)
    const __hip_bfloat16* __restrict__ Wx,    // 4H x KX  (bf16)
    const __hip_bfloat16* __restrict__ Wh,    // 4H x KH  (bf16)
    const float* __restrict__ bih,            // 4H (fp32)
    const float* __restrict__ bhh,            // 4H (fp32)
    const float* __restrict__ c_in,           // NB x NH fp32 or null (=> 0)
    __hip_bfloat16* __restrict__ h_bf,        // NB x NH bf16 (always written)
    float* __restrict__ h_f32,                // NB x NH fp32 or null
    float* __restrict__ c_out)                // NB x NH fp32 or null
{
    constexpr int K = KX + KH;
    constexpr int NCH = K / 32;
    const int bu = blockIdx.x % (NH / 16);    // unit tile (48)
    const int bm = blockIdx.x / (NH / 16);    // batch half (2)
    const int u0 = bu * 16;
    const int tid = threadIdx.x;
    const int g = tid >> 6;                   // wave index == gate index
    const int lane = tid & 63;
    const int r = lane & 15;
    const int q = lane >> 4;

    f32x4 acc0 = {0.f, 0.f, 0.f, 0.f};
    f32x4 acc1 = {0.f, 0.f, 0.f, 0.f};

    const int row0 = bm * 32 + r;             // A rows for the two 16-row m-tiles
    const int row1 = row0 + 16;
    const long wr = (long)(g * NH + u0 + r);  // weight row for B-frag column r

    #pragma unroll
    for (int c = 0; c < NCH; ++c) {
        const int k0 = c * 32;
        bf16x8 a0, a1, bfrag;
        if (k0 < KX) {
            const int kk = k0 + q * 8;
            a0 = *(const bf16x8*)(xin + (long)row0 * KX + kk);
            a1 = *(const bf16x8*)(xin + (long)row1 * KX + kk);
            bfrag = *(const bf16x8*)(Wx + wr * KX + kk);
        } else {
            const int kk = (k0 - KX) + q * 8;
            a0 = *(const bf16x8*)(hin + (long)row0 * KH + kk);
            a1 = *(const bf16x8*)(hin + (long)row1 * KH + kk);
            bfrag = *(const bf16x8*)(Wh + wr * KH + kk);
        }
        acc0 = __builtin_amdgcn_mfma_f32_16x16x32_bf16(a0, bfrag, acc0, 0, 0, 0);
        acc1 = __builtin_amdgcn_mfma_f32_16x16x32_bf16(a1, bfrag, acc1, 0, 0, 0);
    }

    // C/D layout: col = lane&15 (unit), row = (lane>>4)*4 + reg (local batch)
    __shared__ float gbuf[4][32][17];
    #pragma unroll
    for (int i = 0; i < 4; ++i) {
        gbuf[g][q * 4 + i][r]      = acc0[i];
        gbuf[g][16 + q * 4 + i][r] = acc1[i];
    }
    __syncthreads();

    // fused cell: 32 batch x 16 units = 512 cells, 2 per thread
    #pragma unroll
    for (int i = 0; i < 2; ++i) {
        const int idx = tid + i * 256;
        const int bl = idx >> 4;
        const int u  = idx & 15;
        const int gu = u0 + u;
        const int b  = bm * 32 + bl;
        const float pi = gbuf[0][bl][u] + bih[gu]          + bhh[gu];
        const float pf = gbuf[1][bl][u] + bih[NH + gu]     + bhh[NH + gu];
        const float pg = gbuf[2][bl][u] + bih[2 * NH + gu] + bhh[2 * NH + gu];
        const float po = gbuf[3][bl][u] + bih[3 * NH + gu] + bhh[3 * NH + gu];
        const float cp = c_in ? c_in[(long)b * NH + gu] : 0.f;
        const float cn = sigm(pf) * cp + sigm(pi) * tanhf(pg);
        const float hn = sigm(po) * tanhf(cn);
        if (c_out) c_out[(long)b * NH + gu] = cn;
        if (h_f32) h_f32[(long)b * NH + gu] = hn;
        h_bf[(long)b * NH + gu] = __float2bfloat16(hn);
    }
}

// Decoder recurrence step on a single 768-vector (batch/layer-independent).
// One wave per unit; f-gate skipped (c_prev == 0). Pure fp32.
__global__ __launch_bounds__(64) void dec_step(
    const float* __restrict__ h_in,           // NH
    const float* __restrict__ W,              // 4H x NH (decoder layer L-1)
    const float* __restrict__ bih,            // 4H
    const float* __restrict__ bhh,            // 4H
    float* __restrict__ h_out,                // NH
    float* __restrict__ h_store)              // NH (archive for the head)
{
    const int u = blockIdx.x;
    const int lane = threadIdx.x;
    float ai = 0.f, ag = 0.f, ao = 0.f;
    const float* Wi = W + (size_t)u * NH;
    const float* Wg = W + (size_t)(2 * NH + u) * NH;
    const float* Wo = W + (size_t)(3 * NH + u) * NH;
    for (int k = lane; k < NH; k += 64) {
        const float hv = h_in[k];
        ai += hv * Wi[k];
        ag += hv * Wg[k];
        ao += hv * Wo[k];
    }
    #pragma unroll
    for (int off = 32; off > 0; off >>= 1) {
        ai += __shfl_xor(ai, off);
        ag += __shfl_xor(ag, off);
        ao += __shfl_xor(ao, off);
    }
    if (lane == 0) {
        const float pi = ai + bih[u]          + bhh[u];
        const float pg = ag + bih[2 * NH + u] + bhh[2 * NH + u];
        const float po = ao + bih[3 * NH + u] + bhh[3 * NH + u];
        const float cn = sigm(pi) * tanhf(pg);
        const float hn = sigm(po) * tanhf(cn);
        h_out[u] = hn;
        h_store[u] = hn;
    }
}

// Head: out[t,b,f] = hdec_all[t]@lin_W^T + lin_b, broadcast over batch.
__global__ __launch_bounds__(256) void head_kernel(
    const float* __restrict__ hall,           // NT x NH
    const float* __restrict__ lw,             // NF x NH
    const float* __restrict__ lb,             // NF
    float* __restrict__ out)                  // NT x NB x NF
{
    const int t = blockIdx.x;
    const int f = threadIdx.x;
    const float* h = hall + (size_t)t * NH;
    const float4* wrow = (const float4*)(lw + (size_t)f * NH);
    float acc = 0.f;
    for (int k4 = 0; k4 < NH / 4; ++k4) {
        const float4 w = wrow[k4];
        acc += h[k4 * 4]     * w.x;
        acc += h[k4 * 4 + 1] * w.y;
        acc += h[k4 * 4 + 2] * w.z;
        acc += h[k4 * 4 + 3] * w.w;
    }
    acc += lb[f];
    float* o = out + (size_t)t * NB * NF + f;
    for (int b = 0; b < NB; ++b) o[(size_t)b * NF] = acc;
}

extern "C" void kernel_launch(void* const* d_in, const int* in_sizes, int n_in,
                              void* d_out, int out_size, void* d_ws, size_t ws_size,
                              hipStream_t stream) {
    (void)in_sizes; (void)n_in; (void)out_size; (void)ws_size;
    const float* x     = (const float*)d_in[0];
    const float* eWih0 = (const float*)d_in[1];
    const float* eWhh0 = (const float*)d_in[2];
    const float* ebih0 = (const float*)d_in[3];
    const float* ebhh0 = (const float*)d_in[4];
    const float* eWih  = (const float*)d_in[5];
    // d_in[6] = e_Whh : provably unused (zero state, seq_len=1)
    const float* ebih  = (const float*)d_in[7];
    const float* ebhh  = (const float*)d_in[8];
    const float* dWih  = (const float*)d_in[9];
    // d_in[10] = d_Whh : provably unused
    const float* dbih  = (const float*)d_in[11];
    const float* dbhh  = (const float*)d_in[12];
    const float* linW  = (const float*)d_in[13];
    const float* linb  = (const float*)d_in[14];
    // d_in[15] = target_len (fixed 32, matches out_size)
    float* out = (float*)d_out;

    // ---- workspace layout (bytes), ~23.7 MiB total ----
    char* ws = (char*)d_ws;
    __hip_bfloat16* xb   = (__hip_bfloat16*)(ws);              // x bf16: 4,194,304 el
    __hip_bfloat16* W0x  = (__hip_bfloat16*)(ws +  8388608);   // Wih0:     786,432 el
    __hip_bfloat16* W0h  = (__hip_bfloat16*)(ws +  9961472);   // Whh0:   2,359,296 el
    __hip_bfloat16* eW12 = (__hip_bfloat16*)(ws + 14680064);   // eWih:   4,718,592 el
    __hip_bfloat16* hb0  = (__hip_bfloat16*)(ws + 24117248);   // 64x768 bf16
    __hip_bfloat16* hb1  = (__hip_bfloat16*)(ws + 24215552);
    float* cb0  = (float*)(ws + 24313856);                     // 64x768 f32
    float* cb1  = (float*)(ws + 24510464);
    float* hd0  = (float*)(ws + 24707072);                     // 768 f32
    float* hd1  = (float*)(ws + 24710144);
    float* hall = (float*)(ws + 24713216);                     // 32x768 f32

    // ws is poisoned 0xAA before every launch: zero the initial states
    hipMemsetAsync(hb0, 0, (size_t)NB * NH * 2, stream);
    hipMemsetAsync(cb0, 0, (size_t)NB * NH * 4, stream);
    hipMemsetAsync(hd0, 0, (size_t)NH * 4, stream);

    // one-time fp32 -> bf16 conversions (off the sequential critical path)
    cvt_f32_bf16<<<(NS * NB * NF) / 1024, 256, 0, stream>>>(x, xb, NS * NB * NF);
    cvt_f32_bf16<<<(4 * NH * NF) / 1024, 256, 0, stream>>>(eWih0, W0x, 4 * NH * NF);
    cvt_f32_bf16<<<(4 * NH * NH) / 1024, 256, 0, stream>>>(eWhh0, W0h, 4 * NH * NH);
    cvt_f32_bf16<<<(2 * 4 * NH * NH) / 1024, 256, 0, stream>>>(eWih, eW12, 2 * 4 * NH * NH);

    __hip_bfloat16* hb[2] = {hb0, hb1};
    float* cb[2] = {cb0, cb1};
    float* enc = out + (size_t)NT * NB * NF;                   // encoder_hidden slab

    // encoder layer 0: 256 sequential steps (the critical path)
    for (int t = 0; t < NS; ++t) {
        const bool last = (t == NS - 1);
        lstm_step<NF, NH><<<96, 256, 0, stream>>>(
            xb + (size_t)t * NB * NF, hb[t & 1], W0x, W0h, ebih0, ebhh0,
            cb[t & 1], hb[(t + 1) & 1], last ? enc : nullptr,
            last ? nullptr : cb[(t + 1) & 1]);
    }
    // encoder layers 1..2: single step, zero state, Whh dead
    lstm_step<NH, 0><<<96, 256, 0, stream>>>(
        hb[0], nullptr, eW12, nullptr, ebih, ebhh,
        nullptr, hb[1], enc + NB * NH, nullptr);
    lstm_step<NH, 0><<<96, 256, 0, stream>>>(
        hb[1], nullptr, eW12 + (size_t)4 * NH * NH, nullptr,
        ebih + 4 * NH, ebhh + 4 * NH,
        nullptr, hb[0], enc + 2 * (size_t)NB * NH, nullptr);

    // decoder: single-vector recurrence on last layer only (fp32 weights direct)
    const float* W2 = dWih + (size_t)2 * 4 * NH * NH;
    float* hd[2] = {hd0, hd1};
    for (int t = 0; t < NT; ++t) {
        dec_step<<<NH, 64, 0, stream>>>(hd[t & 1], W2, dbih + 2 * 4 * NH,
                                        dbhh + 2 * 4 * NH,
                                        hd[(t + 1) & 1], hall + (size_t)t * NH);
    }
    // head + batch broadcast
    head_kernel<<<NT, NF, 0, stream>>>(hall, linW, linb, out);
}